// Round 9
// baseline (1119.567 us; speedup 1.0000x reference)
//
#include <hip/hip_runtime.h>
#include <math.h>
#include <stdint.h>

#define D_MODEL 256
#define NH 8
#define HD 32
#define NL 4
#define NP 4
#define DFF 1024
#define NLAYERS 6
#define BS 2
#define S_TOK 13294
#define MTOT (BS * S_TOK)   // 26588
#define MPAD 26624          // 208 * 128

typedef unsigned short u16;
typedef __attribute__((ext_vector_type(8))) __bf16 bf16x8;
typedef __attribute__((ext_vector_type(4))) float f32x4;

#define AS1 __attribute__((address_space(1)))
#define AS3 __attribute__((address_space(3)))

__device__ inline u16 bf16_rne(float f) {
    union { float f; uint32_t u; } v; v.f = f;
    uint32_t u = v.u;
    return (u16)((u + 0x7FFFu + ((u >> 16) & 1u)) >> 16);
}
__device__ inline float bf16_to_f(u16 h) {
    union { uint32_t u; float f; } v; v.u = (uint32_t)h << 16; return v.f;
}

// ---------------------------------------------------------------------------
// Weight prep: bf16, transposed to [N][K]. Per-layer segments (elements):
//   [QAV: (Wo|Wa|Wv) 640*256][OUT: 256*256][F1: 1024*256][F2: 256*1024]
// ---------------------------------------------------------------------------
#define WT_L 753664
#define WT_OA2 0
#define WT_OV 98304
#define WT_OOUT 163840
#define WT_OF1 229376
#define WT_OF2 491520

__global__ void wprep_kernel(const float* __restrict__ Wv, const float* __restrict__ Wo,
                             const float* __restrict__ Wa, const float* __restrict__ Wout,
                             const float* __restrict__ Wf1, const float* __restrict__ Wf2,
                             u16* __restrict__ dst)
{
    int idx = blockIdx.x * blockDim.x + threadIdx.x;
    if (idx >= NLAYERS * WT_L) return;
    int l = idx / WT_L;
    int r = idx - l * WT_L;
    float val;
    if (r < WT_OV) {                       // cols 0-255 = Wo, 256-383 = Wa
        int n = r >> 8, k = r & 255;
        if (n < 256) val = Wo[(size_t)l * 65536 + k * 256 + n];
        else         val = Wa[(size_t)l * 32768 + k * 128 + (n - 256)];
    } else if (r < WT_OOUT) {              // 384-639 = Wv
        int sr = r - WT_OV; int n = sr >> 8, k = sr & 255;
        val = Wv[(size_t)l * 65536 + k * 256 + n];
    } else if (r < WT_OF1) {
        int sr = r - WT_OOUT; int n = sr >> 8, k = sr & 255;
        val = Wout[(size_t)l * 65536 + k * 256 + n];
    } else if (r < WT_OF2) {
        int sr = r - WT_OF1; int n = sr >> 8, k = sr & 255;       // N=1024, K=256
        val = Wf1[(size_t)l * 262144 + k * 1024 + n];
    } else {
        int sr = r - WT_OF2; int n = sr >> 10, k = sr & 1023;     // N=256, K=1024
        val = Wf2[(size_t)l * 262144 + k * 256 + n];
    }
    dst[(size_t)l * WT_L + r] = bf16_rne(val);
}

// ---------------------------------------------------------------------------
__global__ void refpoints_kernel(const float* __restrict__ vr, float* __restrict__ ref)
{
    int t = blockIdx.x * blockDim.x + threadIdx.x;
    if (t >= MTOT) return;
    int b = t / S_TOK;
    int s = t - b * S_TOK;
    int lvl, W, H, start;
    if (s < 10000)      { lvl = 0; W = 100; H = 100; start = 0; }
    else if (s < 12500) { lvl = 1; W = 50;  H = 50;  start = 10000; }
    else if (s < 13125) { lvl = 2; W = 25;  H = 25;  start = 12500; }
    else                { lvl = 3; W = 13;  H = 13;  start = 13125; }
    int wi = s - start;
    int y = wi / W;
    int x = wi - y * W;
    float rx = (x + 0.5f) / (vr[(b * NL + lvl) * 2 + 0] * (float)W);
    float ry = (y + 0.5f) / (vr[(b * NL + lvl) * 2 + 1] * (float)H);
#pragma unroll
    for (int l2 = 0; l2 < NL; l2++) {
        ref[((size_t)t * NL + l2) * 2 + 0] = rx * vr[(b * NL + l2) * 2 + 0];
        ref[((size_t)t * NL + l2) * 2 + 1] = ry * vr[(b * NL + l2) * 2 + 1];
    }
}

// ---------------------------------------------------------------------------
// conv0: Xb = bf16(src), Qb = bf16(src+pos), posb = bf16(pos)
// ---------------------------------------------------------------------------
__global__ void conv0_kernel(const float* __restrict__ src, const float* __restrict__ pos,
                             u16* __restrict__ Xb, u16* __restrict__ Qb, u16* __restrict__ Pb)
{
    int t = blockIdx.x * blockDim.x + threadIdx.x;
    if (t >= MTOT * 64) return;
    float4 s = ((const float4*)src)[t];
    float4 p = ((const float4*)pos)[t];
    ushort4 a, q, pb;
    a.x = bf16_rne(s.x); a.y = bf16_rne(s.y); a.z = bf16_rne(s.z); a.w = bf16_rne(s.w);
    q.x = bf16_rne(s.x + p.x); q.y = bf16_rne(s.y + p.y);
    q.z = bf16_rne(s.z + p.z); q.w = bf16_rne(s.w + p.w);
    pb.x = bf16_rne(p.x); pb.y = bf16_rne(p.y); pb.z = bf16_rne(p.z); pb.w = bf16_rne(p.w);
    ((ushort4*)Xb)[t] = a;
    ((ushort4*)Qb)[t] = q;
    ((ushort4*)Pb)[t] = pb;
}

// ---------------------------------------------------------------------------
// 128x128 BF16 MFMA GEMM, BK=64 (4 stage->barrier steps at K=256 instead of 8
// -- the r8 gemm_ln lesson: fewer barrier vmcnt-drains at low blocks/CU),
// chunk-XOR swizzle c ^= row&7 on both the pre-swizzled global source and the
// ds_read chunk (LDS linear, rule #21). LDS 32 KB -> 5 blocks/CU.
// MODE 2 (ff1): C0 = bf16(relu(A@Bt^T + bias)), stride N.
// MODE 4 (QAV fused, N=640): block-uniform by n0:
//   n0<256: A=Aq f32 C0 s256; n0==256: A=Aq f32 C1 s128; n0>=384: A=Ax bf16 C2 s256.
// XCD-chunk bijective block swizzle.
// ---------------------------------------------------------------------------
template<int MODE>
__global__ __launch_bounds__(256) void gemm_bf16(
    const u16* __restrict__ Aq, const u16* __restrict__ Ax,
    const u16* __restrict__ Bt,
    const float* __restrict__ bias, const float* __restrict__ bias2,
    const float* __restrict__ bias3,
    void* __restrict__ C0, void* __restrict__ C1, void* __restrict__ C2,
    int N, int K)
{
    __shared__ __align__(16) u16 As[128 * 64];   // 16 KB
    __shared__ __align__(16) u16 Bs[128 * 64];   // 16 KB

    const int tid = threadIdx.x;
    const int wid = tid >> 6;
    const int lane = tid & 63;

    const int nwg = gridDim.x * gridDim.y;
    const int bid = blockIdx.y * gridDim.x + blockIdx.x;
    const int q = nwg >> 3, rr = nwg & 7;
    const int xcd = bid & 7, cidx = bid >> 3;
    const int wg = (xcd < rr ? xcd * (q + 1) : rr * (q + 1) + (xcd - rr) * q) + cidx;
    const int m0 = (wg / gridDim.x) * 128;
    const int n0 = (wg % gridDim.x) * 128;
    const int wr = wid >> 1, wc = wid & 1;

    f32x4 acc[4][4] = {};

    // staging: slot(row = ii*32 + (tid>>3), chunk = tid&7); global chunk
    // pre-swizzled: (tid&7) ^ (row&7) = (tid&7) ^ ((tid>>3)&7)  (ii*32 ≡ 0 mod 8)
    const int csw = ((tid & 7) ^ ((tid >> 3) & 7)) * 8;
    const u16* Ause = (MODE == 4 && n0 >= 384) ? Ax : Aq;
    const u16* a0 = Ause + (size_t)(m0 + (tid >> 3)) * K + csw;
    const u16* b0 = Bt + (size_t)(n0 + (tid >> 3)) * K + csw;

    const int gsel = lane >> 4;
    const int rsel = lane & 15;
    const int swz = rsel & 7;

    for (int k0 = 0; k0 < K; k0 += 64) {
#pragma unroll
        for (int ii = 0; ii < 4; ii++) {
            __builtin_amdgcn_global_load_lds((AS1 void*)(a0 + (size_t)(ii * 32) * K + k0),
                                             (AS3 void*)(As + ii * 2048 + wid * 512), 16, 0, 0);
            __builtin_amdgcn_global_load_lds((AS1 void*)(b0 + (size_t)(ii * 32) * K + k0),
                                             (AS3 void*)(Bs + ii * 2048 + wid * 512), 16, 0, 0);
        }
        __syncthreads();

#pragma unroll
        for (int s = 0; s < 2; s++) {          // k sub-step: chunk base cb = s*4
            const int cb = s * 4;
            bf16x8 af[4], bfr[4];
#pragma unroll
            for (int i = 0; i < 4; i++) {
                af[i]  = *reinterpret_cast<const bf16x8*>(
                    &As[(wr * 64 + i * 16 + rsel) * 64 + (((cb + gsel) ^ swz) * 8)]);
                bfr[i] = *reinterpret_cast<const bf16x8*>(
                    &Bs[(wc * 64 + i * 16 + rsel) * 64 + (((cb + gsel) ^ swz) * 8)]);
            }
#pragma unroll
            for (int i = 0; i < 4; i++)
#pragma unroll
                for (int j = 0; j < 4; j++)
                    acc[i][j] = __builtin_amdgcn_mfma_f32_16x16x32_bf16(af[i], bfr[j], acc[i][j], 0, 0, 0);
        }
        __syncthreads();
    }

#pragma unroll
    for (int j = 0; j < 4; j++) {
        int col = n0 + wc * 64 + j * 16 + rsel;
        float bv;
        if (MODE == 4) bv = (n0 < 256) ? bias[col] : (n0 == 256) ? bias2[col - 256] : bias3[col - 384];
        else bv = bias[col];
#pragma unroll
        for (int i = 0; i < 4; i++) {
            int rbase = m0 + wr * 64 + i * 16 + gsel * 4;
#pragma unroll
            for (int r2 = 0; r2 < 4; r2++) {
                int gm = rbase + r2;
                float v = acc[i][j][r2] + bv;
                if (MODE == 2) {
                    v = fmaxf(v, 0.f);
                    ((u16*)C0)[(size_t)gm * N + col] = bf16_rne(v);
                } else {
                    if (n0 < 256)       ((float*)C0)[(size_t)gm * 256 + col] = v;
                    else if (n0 == 256) ((float*)C1)[(size_t)gm * 128 + col - 256] = v;
                    else                ((u16*)C2)[(size_t)gm * 256 + col - 384] = bf16_rne(v);
                }
            }
        }
    }
}

// ---------------------------------------------------------------------------
// BM=32 x BN=256 GEMM + fused residual-add + LayerNorm. BK=64, chunk-XOR
// swizzle (r8-proven). Grid = MPAD/32 = 832 blocks.
// LNMODE 1 (W_out+LN1): y = LN(Xres + A@Bt^T + bias); writes dstf f32 + dstb bf16.
// LNMODE 2 (ff2+LN2):   additionally writes dstq = bf16(y + posb16).
// ---------------------------------------------------------------------------
template<int LNMODE>
__global__ __launch_bounds__(256) void gemm_ln(
    const u16* __restrict__ A, const u16* __restrict__ Bt,
    const float* __restrict__ bias,
    const float* __restrict__ Xres, const float* __restrict__ g,
    const float* __restrict__ be, const u16* __restrict__ posb,
    float* __restrict__ dstf, u16* __restrict__ dstb, u16* __restrict__ dstq,
    int K, int Mguard)
{
    __shared__ __align__(16) u16 As[32 * 64];    // 4 KB
    __shared__ __align__(16) u16 Bs[256 * 64];   // 32 KB
    __shared__ float redS[32][4], redQ[32][4], mrow[32], irow[32];

    const int tid = threadIdx.x;
    const int wid = tid >> 6;
    const int wc = wid;
    const int lane = tid & 63;

    const int nwg = gridDim.x;          // 832, % 8 == 0
    const int q = nwg >> 3;
    const int wg = (blockIdx.x & 7) * q + (blockIdx.x >> 3);
    const int m0 = wg * 32;

    f32x4 acc[2][4] = {};

    // staging: slot(row=tid>>3, chunk=tid&7) sources global chunk (tid&7)^((tid>>3)&7)
    const int csw = ((tid & 7) ^ ((tid >> 3) & 7)) * 8;
    const u16* a0 = A + (size_t)(m0 + (tid >> 3)) * K + csw;
    const u16* b0 = Bt + (size_t)(tid >> 3) * K + csw;

    const int gsel = lane >> 4;         // 0..3
    const int rsel = lane & 15;
    const int swz = rsel & 7;

    for (int k0 = 0; k0 < K; k0 += 64) {
        // A: 256 chunks = 1 gload/thread; wave w covers slots w*64..w*64+63
        __builtin_amdgcn_global_load_lds((AS1 void*)(a0 + k0),
                                         (AS3 void*)(As + wid * 512), 16, 0, 0);
        // B: 2048 chunks = 8 passes
#pragma unroll
        for (int ii = 0; ii < 8; ii++)
            __builtin_amdgcn_global_load_lds((AS1 void*)(b0 + (size_t)ii * 32 * K + k0),
                                             (AS3 void*)(Bs + ii * 2048 + wid * 512), 16, 0, 0);
        __syncthreads();

#pragma unroll
        for (int s = 0; s < 2; s++) {            // kk = s*32, chunk base cb = s*4
            const int cb = s * 4;
            bf16x8 af[2], bfr[4];
#pragma unroll
            for (int i = 0; i < 2; i++)
                af[i] = *reinterpret_cast<const bf16x8*>(
                    &As[(i * 16 + rsel) * 64 + (((cb + gsel) ^ swz) * 8)]);
#pragma unroll
            for (int j = 0; j < 4; j++)
                bfr[j] = *reinterpret_cast<const bf16x8*>(
                    &Bs[(wc * 64 + j * 16 + rsel) * 64 + (((cb + gsel) ^ swz) * 8)]);
#pragma unroll
            for (int i = 0; i < 2; i++)
#pragma unroll
                for (int j = 0; j < 4; j++)
                    acc[i][j] = __builtin_amdgcn_mfma_f32_16x16x32_bf16(af[i], bfr[j], acc[i][j], 0, 0, 0);
        }
        __syncthreads();
    }

    float bias_j[4], g_j[4], be_j[4];
#pragma unroll
    for (int j = 0; j < 4; j++) {
        int col = wc * 64 + j * 16 + rsel;
        bias_j[j] = bias[col]; g_j[j] = g[col]; be_j[j] = be[col];
    }

    // fold bias + residual into acc; butterfly row-sums over the 16 rsel lanes
#pragma unroll
    for (int i = 0; i < 2; i++)
#pragma unroll
    for (int r = 0; r < 4; r++) {
        int row = i * 16 + gsel * 4 + r;
        int grow = m0 + row;
        float s = 0.f, qq = 0.f;
#pragma unroll
        for (int j = 0; j < 4; j++) {
            int col = wc * 64 + j * 16 + rsel;
            float xr = (grow < MTOT) ? Xres[(size_t)grow * 256 + col] : 0.f;
            float v = acc[i][j][r] + bias_j[j] + xr;
            acc[i][j][r] = v;
            s += v; qq += v * v;
        }
#pragma unroll
        for (int m = 1; m <= 8; m <<= 1) {
            s += __shfl_xor(s, m, 64);
            qq += __shfl_xor(qq, m, 64);
        }
        if (rsel == 0) { redS[row][wc] = s; redQ[row][wc] = qq; }
    }
    __syncthreads();
    if (tid < 32) {
        float s  = redS[tid][0] + redS[tid][1] + redS[tid][2] + redS[tid][3];
        float qq = redQ[tid][0] + redQ[tid][1] + redQ[tid][2] + redQ[tid][3];
        float mean = s * (1.f / 256.f);
        float var  = qq * (1.f / 256.f) - mean * mean;
        mrow[tid] = mean;
        irow[tid] = rsqrtf(var + 1e-5f);
    }
    __syncthreads();

#pragma unroll
    for (int i = 0; i < 2; i++)
#pragma unroll
    for (int r = 0; r < 4; r++) {
        int row = i * 16 + gsel * 4 + r;
        int grow = m0 + row;
        if (grow >= Mguard) continue;
        float mean = mrow[row], inv = irow[row];
#pragma unroll
        for (int j = 0; j < 4; j++) {
            int col = wc * 64 + j * 16 + rsel;
            float y = (acc[i][j][r] - mean) * inv * g_j[j] + be_j[j];
            dstf[(size_t)grow * 256 + col] = y;
            dstb[(size_t)grow * 256 + col] = bf16_rne(y);
            if (LNMODE == 2) {
                float pv = (grow < MTOT) ? bf16_to_f(posb[(size_t)grow * 256 + col]) : 0.f;
                dstq[(size_t)grow * 256 + col] = bf16_rne(y + pv);
            }
        }
    }
}

// ---------------------------------------------------------------------------
// Multi-scale deformable sampling with inline softmax (r5/r7/r8-proven);
// value bf16, 4 threads per (b,s,h), 8 channels each; XCD-chunk swizzle.
// ---------------------------------------------------------------------------
__global__ __launch_bounds__(256) void msdeform_kernel(
    const u16* __restrict__ value, const float* __restrict__ off,
    const float* __restrict__ logits, const float* __restrict__ ref,
    u16* __restrict__ out)
{
    const int total = MTOT * NH * 4;
    const int Q = 415, R = 4;
    int bid = blockIdx.x;
    int xcd = bid & 7, cidx = bid >> 3;
    int wg = (xcd < R ? xcd * (Q + 1) : R * (Q + 1) + (xcd - R) * Q) + cidx;
    int t = wg * 256 + (int)threadIdx.x;
    if (t >= total) return;
    int c8 = t & 3;
    int h  = (t >> 2) & 7;
    int bs = t >> 5;
    int b  = (bs >= S_TOK) ? 1 : 0;

    const int Ws[4] = {100, 50, 25, 13};
    const int Hs[4] = {100, 50, 25, 13};
    const int st[4] = {0, 10000, 12500, 13125};

    const float* offp = off    + ((size_t)bs * NH + h) * 32;
    const float* lgp  = logits + ((size_t)bs * NH + h) * 16;
    const float* refp = ref    + (size_t)bs * NL * 2;

    float lw[16];
    {
        float4 a0 = ((const float4*)lgp)[0];
        float4 a1 = ((const float4*)lgp)[1];
        float4 a2 = ((const float4*)lgp)[2];
        float4 a3 = ((const float4*)lgp)[3];
        lw[0]=a0.x; lw[1]=a0.y; lw[2]=a0.z; lw[3]=a0.w;
        lw[4]=a1.x; lw[5]=a1.y; lw[6]=a1.z; lw[7]=a1.w;
        lw[8]=a2.x; lw[9]=a2.y; lw[10]=a2.z; lw[11]=a2.w;
        lw[12]=a3.x; lw[13]=a3.y; lw[14]=a3.z; lw[15]=a3.w;
        float mx = lw[0];
#pragma unroll
        for (int i = 1; i < 16; i++) mx = fmaxf(mx, lw[i]);
        float s = 0.f;
#pragma unroll
        for (int i = 0; i < 16; i++) { lw[i] = __expf(lw[i] - mx); s += lw[i]; }
        float inv = 1.f / s;
#pragma unroll
        for (int i = 0; i < 16; i++) lw[i] *= inv;
    }

    float acc[8] = {};

#pragma unroll
    for (int l = 0; l < NL; l++) {
        const int W = Ws[l], H = Hs[l];
        const u16* vbase = value + ((size_t)b * S_TOK + st[l]) * D_MODEL + h * HD + c8 * 8;
        const float fW = (float)W, fH = (float)H;
        const float rxw = fmaf(refp[l * 2 + 0], fW, -0.5f);
        const float ryh = fmaf(refp[l * 2 + 1], fH, -0.5f);
#pragma unroll
        for (int p = 0; p < NP; p++) {
            float x = rxw + offp[l * 8 + p * 2 + 0];
            float y = ryh + offp[l * 8 + p * 2 + 1];
            float a = lw[l * 4 + p];
            float x0f = floorf(x), y0f = floorf(y);
            float wx1 = x - x0f, wy1 = y - y0f;
            float wx0 = 1.f - wx1, wy0 = 1.f - wy1;
            int ix0 = (int)x0f, iy0 = (int)y0f;
#pragma unroll
            for (int dy = 0; dy < 2; dy++) {
                int yi = iy0 + dy;
                if (yi < 0 || yi >= H) continue;
                float wy = dy ? wy1 : wy0;
#pragma unroll
                for (int dx = 0; dx < 2; dx++) {
                    int xi = ix0 + dx;
                    if (xi < 0 || xi >= W) continue;
                    float wgt = (dx ? wx1 : wx0) * wy * a;
                    uint4 gv = *(const uint4*)(vbase + (size_t)(yi * W + xi) * D_MODEL);
                    union { uint32_t q; float f; } lo, hi;
                    lo.q = gv.x << 16; hi.q = gv.x & 0xffff0000u;
                    acc[0] = fmaf(lo.f, wgt, acc[0]); acc[1] = fmaf(hi.f, wgt, acc[1]);
                    lo.q = gv.y << 16; hi.q = gv.y & 0xffff0000u;
                    acc[2] = fmaf(lo.f, wgt, acc[2]); acc[3] = fmaf(hi.f, wgt, acc[3]);
                    lo.q = gv.z << 16; hi.q = gv.z & 0xffff0000u;
                    acc[4] = fmaf(lo.f, wgt, acc[4]); acc[5] = fmaf(hi.f, wgt, acc[5]);
                    lo.q = gv.w << 16; hi.q = gv.w & 0xffff0000u;
                    acc[6] = fmaf(lo.f, wgt, acc[6]); acc[7] = fmaf(hi.f, wgt, acc[7]);
                }
            }
        }
    }
    uint4 o;
    o.x = ((uint32_t)bf16_rne(acc[1]) << 16) | bf16_rne(acc[0]);
    o.y = ((uint32_t)bf16_rne(acc[3]) << 16) | bf16_rne(acc[2]);
    o.z = ((uint32_t)bf16_rne(acc[5]) << 16) | bf16_rne(acc[4]);
    o.w = ((uint32_t)bf16_rne(acc[7]) << 16) | bf16_rne(acc[6]);
    ((uint4*)out)[((size_t)bs * NH + h) * 4 + c8] = o;
}

// ---------------------------------------------------------------------------
extern "C" void kernel_launch(void* const* d_in, const int* in_sizes, int n_in,
                              void* d_out, int out_size, void* d_ws, size_t ws_size,
                              hipStream_t stream)
{
    const float* src    = (const float*)d_in[0];
    const float* pos    = (const float*)d_in[1];
    const float* vr     = (const float*)d_in[2];
    const float* W_off  = (const float*)d_in[3];
    const float* b_off  = (const float*)d_in[4];
    const float* W_attn = (const float*)d_in[5];
    const float* b_attn = (const float*)d_in[6];
    const float* W_val  = (const float*)d_in[7];
    const float* b_val  = (const float*)d_in[8];
    const float* W_out  = (const float*)d_in[9];
    const float* b_out  = (const float*)d_in[10];
    const float* g1     = (const float*)d_in[11];
    const float* be1    = (const float*)d_in[12];
    const float* W_ff1  = (const float*)d_in[13];
    const float* b_ff1  = (const float*)d_in[14];
    const float* W_ff2  = (const float*)d_in[15];
    const float* b_ff2  = (const float*)d_in[16];
    const float* g2     = (const float*)d_in[17];
    const float* be2    = (const float*)d_in[18];
    float* out = (float*)d_out;

    uint8_t* wp = (uint8_t*)d_ws;
    auto alloc = [&](size_t bytes) { uint8_t* p = wp; wp += (bytes + 255) & ~(size_t)255; return p; };
    float* refb   = (float*)alloc((size_t)MTOT * 8 * 4);
    float* Ybuf   = (float*)alloc((size_t)MPAD * 256 * 4);
    float* Xf     = (float*)alloc((size_t)MPAD * 256 * 4);
    // [offb | attb | valb16] contiguous: all dead during FFN -> aliased by ffb16
    float* offb   = (float*)alloc((size_t)MPAD * 256 * 4);
    float* attb   = (float*)alloc((size_t)MPAD * 128 * 4);
    u16*   valb16 = (u16*)alloc((size_t)MPAD * 256 * 2);
    uint8_t* slabB = alloc((size_t)MPAD * 256 * 2);         // Xb16 / samb16
    uint8_t* slabC = alloc((size_t)MPAD * 256 * 2);         // Qb16 / Yb16
    u16*   posb16 = (u16*)alloc((size_t)MPAD * 256 * 2);
    u16* Wt = (u16*)alloc((size_t)NLAYERS * WT_L * 2);

    u16* Xb16   = (u16*)slabB;
    u16* samb16 = (u16*)slabB;
    u16* Qb16   = (u16*)slabC;
    u16* Yb16   = (u16*)slabC;
    u16* ffb16  = (u16*)offb;   // 27.25 + 13.63 + 13.63 MB == MPAD*1024*2 B exactly

    const int GY = MPAD / 128;            // 208
    const int GLN = MPAD / 32;            // 832
    const int MSD_BLOCKS = (MTOT * NH * 4 + 255) / 256;  // 3324

    wprep_kernel<<<(NLAYERS * WT_L + 255) / 256, 256, 0, stream>>>(
        W_val, W_off, W_attn, W_out, W_ff1, W_ff2, Wt);
    refpoints_kernel<<<(MTOT + 255) / 256, 256, 0, stream>>>(vr, refb);
    conv0_kernel<<<(MTOT * 64 + 255) / 256, 256, 0, stream>>>(src, pos, Xb16, Qb16, posb16);

    for (int l = 0; l < NLAYERS; l++) {
        const float* Xres = (l == 0) ? src : Xf;
        const u16* Wl = Wt + (size_t)l * WT_L;

        // off|attn|value fused: Q @ [Wo|Wa] and X @ Wv, one dispatch (N=640)
        gemm_bf16<4><<<dim3(5, GY), 256, 0, stream>>>(
            Qb16, Xb16, Wl + WT_OA2,
            b_off + l * 256, b_attn + l * 128, b_val + l * 256,
            offb, attb, valb16, 640, 256);
        // sampled -> samb16 (overwrites dead Xb16); softmax fused inside
        msdeform_kernel<<<MSD_BLOCKS, 256, 0, stream>>>(
            valb16, offb, attb, refb, samb16);
        // Y = LN(Xres + sampled @ W_out + b_out): fused epilogue, BM=32/BK=64
        gemm_ln<1><<<GLN, 256, 0, stream>>>(
            samb16, Wl + WT_OOUT, b_out + l * 256,
            Xres, g1 + l * 256, be1 + l * 256, nullptr,
            Ybuf, Yb16, nullptr, 256, MPAD);
        // ff1: bf16 relu(Y @ Wf1 + b), one dispatch into ffb16 (aliases offb..valb16)
        gemm_bf16<2><<<dim3(8, GY), 256, 0, stream>>>(
            Yb16, nullptr, Wl + WT_OF1, b_ff1 + l * DFF, nullptr, nullptr,
            ffb16, nullptr, nullptr, 1024, 256);
        // X' = LN(Y + ff @ Wf2 + b): fused epilogue, BM=32/BK=64
        float* dst = (l == NLAYERS - 1) ? out : Xf;
        int mg = (l == NLAYERS - 1) ? MTOT : MPAD;
        gemm_ln<2><<<GLN, 256, 0, stream>>>(
            ffb16, Wl + WT_OF2, b_ff2 + l * 256,
            Ybuf, g2 + l * 256, be2 + l * 256, posb16,
            dst, Xb16, Qb16, 1024, mg);
    }
}

// Round 10
// 1078.167 us; speedup vs baseline: 1.0384x; 1.0384x over previous
//
#include <hip/hip_runtime.h>
#include <math.h>
#include <stdint.h>

#define D_MODEL 256
#define NH 8
#define HD 32
#define NL 4
#define NP 4
#define DFF 1024
#define NLAYERS 6
#define BS 2
#define S_TOK 13294
#define MTOT (BS * S_TOK)   // 26588
#define MPAD 26624          // 208 * 128

typedef unsigned short u16;
typedef __attribute__((ext_vector_type(8))) __bf16 bf16x8;
typedef __attribute__((ext_vector_type(4))) float f32x4;

#define AS1 __attribute__((address_space(1)))
#define AS3 __attribute__((address_space(3)))

__device__ inline u16 bf16_rne(float f) {
    union { float f; uint32_t u; } v; v.f = f;
    uint32_t u = v.u;
    return (u16)((u + 0x7FFFu + ((u >> 16) & 1u)) >> 16);
}
__device__ inline float bf16_to_f(u16 h) {
    union { uint32_t u; float f; } v; v.u = (uint32_t)h << 16; return v.f;
}

// ---------------------------------------------------------------------------
// Weight prep: bf16, transposed to [N][K]. Per-layer segments (elements):
//   [QAV: (Wo|Wa|Wv) 640*256][OUT: 256*256][F1: 1024*256][F2: 256*1024]
// ---------------------------------------------------------------------------
#define WT_L 753664
#define WT_OA2 0
#define WT_OV 98304
#define WT_OOUT 163840
#define WT_OF1 229376
#define WT_OF2 491520

__global__ void wprep_kernel(const float* __restrict__ Wv, const float* __restrict__ Wo,
                             const float* __restrict__ Wa, const float* __restrict__ Wout,
                             const float* __restrict__ Wf1, const float* __restrict__ Wf2,
                             u16* __restrict__ dst)
{
    int idx = blockIdx.x * blockDim.x + threadIdx.x;
    if (idx >= NLAYERS * WT_L) return;
    int l = idx / WT_L;
    int r = idx - l * WT_L;
    float val;
    if (r < WT_OV) {                       // cols 0-255 = Wo, 256-383 = Wa
        int n = r >> 8, k = r & 255;
        if (n < 256) val = Wo[(size_t)l * 65536 + k * 256 + n];
        else         val = Wa[(size_t)l * 32768 + k * 128 + (n - 256)];
    } else if (r < WT_OOUT) {              // 384-639 = Wv
        int sr = r - WT_OV; int n = sr >> 8, k = sr & 255;
        val = Wv[(size_t)l * 65536 + k * 256 + n];
    } else if (r < WT_OF1) {
        int sr = r - WT_OOUT; int n = sr >> 8, k = sr & 255;
        val = Wout[(size_t)l * 65536 + k * 256 + n];
    } else if (r < WT_OF2) {
        int sr = r - WT_OF1; int n = sr >> 8, k = sr & 255;       // N=1024, K=256
        val = Wf1[(size_t)l * 262144 + k * 1024 + n];
    } else {
        int sr = r - WT_OF2; int n = sr >> 10, k = sr & 1023;     // N=256, K=1024
        val = Wf2[(size_t)l * 262144 + k * 256 + n];
    }
    dst[(size_t)l * WT_L + r] = bf16_rne(val);
}

// ---------------------------------------------------------------------------
__global__ void refpoints_kernel(const float* __restrict__ vr, float* __restrict__ ref)
{
    int t = blockIdx.x * blockDim.x + threadIdx.x;
    if (t >= MTOT) return;
    int b = t / S_TOK;
    int s = t - b * S_TOK;
    int lvl, W, H, start;
    if (s < 10000)      { lvl = 0; W = 100; H = 100; start = 0; }
    else if (s < 12500) { lvl = 1; W = 50;  H = 50;  start = 10000; }
    else if (s < 13125) { lvl = 2; W = 25;  H = 25;  start = 12500; }
    else                { lvl = 3; W = 13;  H = 13;  start = 13125; }
    int wi = s - start;
    int y = wi / W;
    int x = wi - y * W;
    float rx = (x + 0.5f) / (vr[(b * NL + lvl) * 2 + 0] * (float)W);
    float ry = (y + 0.5f) / (vr[(b * NL + lvl) * 2 + 1] * (float)H);
#pragma unroll
    for (int l2 = 0; l2 < NL; l2++) {
        ref[((size_t)t * NL + l2) * 2 + 0] = rx * vr[(b * NL + l2) * 2 + 0];
        ref[((size_t)t * NL + l2) * 2 + 1] = ry * vr[(b * NL + l2) * 2 + 1];
    }
}

// ---------------------------------------------------------------------------
// conv0: Xb = bf16(src), Qb = bf16(src+pos), posb = bf16(pos)
// ---------------------------------------------------------------------------
__global__ void conv0_kernel(const float* __restrict__ src, const float* __restrict__ pos,
                             u16* __restrict__ Xb, u16* __restrict__ Qb, u16* __restrict__ Pb)
{
    int t = blockIdx.x * blockDim.x + threadIdx.x;
    if (t >= MTOT * 64) return;
    float4 s = ((const float4*)src)[t];
    float4 p = ((const float4*)pos)[t];
    ushort4 a, q, pb;
    a.x = bf16_rne(s.x); a.y = bf16_rne(s.y); a.z = bf16_rne(s.z); a.w = bf16_rne(s.w);
    q.x = bf16_rne(s.x + p.x); q.y = bf16_rne(s.y + p.y);
    q.z = bf16_rne(s.z + p.z); q.w = bf16_rne(s.w + p.w);
    pb.x = bf16_rne(p.x); pb.y = bf16_rne(p.y); pb.z = bf16_rne(p.z); pb.w = bf16_rne(p.w);
    ((ushort4*)Xb)[t] = a;
    ((ushort4*)Qb)[t] = q;
    ((ushort4*)Pb)[t] = pb;
}

// ---------------------------------------------------------------------------
// 128x128 BF16 MFMA GEMM, BK=32 (r8-proven base), 2-PHASE double-buffered
// prefetch (T3 minimum recipe): STAGE(next) issued BEFORE the compute phase,
// so global->LDS latency hides under ds_read+MFMA; the compiler's vmcnt-drain
// at the bottom __syncthreads lands AFTER the MFMA phase.  T2 prerequisite
// satisfied: chunk-XOR swizzle c ^= (row>>1)&3 on both the pre-swizzled
// global source and the ds_read chunk (0 bank conflicts since r8).
// MODE 2 (ff1): C0 = bf16(relu(A@Bt^T + bias)), stride N.
// MODE 4 (QAV fused, N=640): block-uniform by n0:
//   n0<256: A=Aq f32 C0 s256; n0==256: A=Aq f32 C1 s128; n0>=384: A=Ax bf16 C2 s256.
// XCD-chunk bijective block swizzle.  LDS 32 KB -> 5 blocks/CU.
// ---------------------------------------------------------------------------
template<int MODE>
__global__ __launch_bounds__(256) void gemm_bf16(
    const u16* __restrict__ Aq, const u16* __restrict__ Ax,
    const u16* __restrict__ Bt,
    const float* __restrict__ bias, const float* __restrict__ bias2,
    const float* __restrict__ bias3,
    void* __restrict__ C0, void* __restrict__ C1, void* __restrict__ C2,
    int N, int K)
{
    __shared__ __align__(16) u16 As[2][128 * 32];
    __shared__ __align__(16) u16 Bs[2][128 * 32];

    const int tid = threadIdx.x;
    const int wid = tid >> 6;
    const int lane = tid & 63;

    const int nwg = gridDim.x * gridDim.y;
    const int bid = blockIdx.y * gridDim.x + blockIdx.x;
    const int q = nwg >> 3, rr = nwg & 7;
    const int xcd = bid & 7, cidx = bid >> 3;
    const int wg = (xcd < rr ? xcd * (q + 1) : rr * (q + 1) + (xcd - rr) * q) + cidx;
    const int m0 = (wg / gridDim.x) * 128;
    const int n0 = (wg % gridDim.x) * 128;
    const int wr = wid >> 1, wc = wid & 1;

    f32x4 acc[4][4] = {};

    // staging: slot(row = tid>>2, chunk = tid&3); global chunk pre-swizzled:
    // (tid&3) ^ ((row>>1)&3) = (tid&3) ^ ((tid>>3)&3)
    const int csw = ((tid & 3) ^ ((tid >> 3) & 3)) * 8;
    const u16* Ause = (MODE == 4 && n0 >= 384) ? Ax : Aq;
    const u16* a0 = Ause + (size_t)(m0 + (tid >> 2)) * K + csw;
    const u16* b0 = Bt + (size_t)(n0 + (tid >> 2)) * K + csw;

    const int rsel = lane & 15;
    const int ksw = (((lane >> 4) ^ ((rsel >> 1) & 3))) * 8;

#define GST(buf, kk) do {                                                           \
    u16* asb = &As[buf][wid * 512];                                                 \
    u16* bsb = &Bs[buf][wid * 512];                                                 \
    __builtin_amdgcn_global_load_lds((AS1 void*)(a0 + (kk)), (AS3 void*)(asb), 16, 0, 0); \
    __builtin_amdgcn_global_load_lds((AS1 void*)(a0 + (size_t)64 * K + (kk)),       \
                                     (AS3 void*)(asb + 2048), 16, 0, 0);            \
    __builtin_amdgcn_global_load_lds((AS1 void*)(b0 + (kk)), (AS3 void*)(bsb), 16, 0, 0); \
    __builtin_amdgcn_global_load_lds((AS1 void*)(b0 + (size_t)64 * K + (kk)),       \
                                     (AS3 void*)(bsb + 2048), 16, 0, 0);            \
} while (0)

    GST(0, 0);
    __syncthreads();          // compiler emits vmcnt(0) before barrier -> buf0 ready

    int cur = 0;
    for (int k0 = 0; k0 < K; k0 += 32) {
        if (k0 + 32 < K) GST(cur ^ 1, k0 + 32);   // prefetch flies under compute

        bf16x8 af[4], bfr[4];
#pragma unroll
        for (int i = 0; i < 4; i++) {
            af[i]  = *reinterpret_cast<const bf16x8*>(&As[cur][(wr * 64 + i * 16 + rsel) * 32 + ksw]);
            bfr[i] = *reinterpret_cast<const bf16x8*>(&Bs[cur][(wc * 64 + i * 16 + rsel) * 32 + ksw]);
        }
#pragma unroll
        for (int i = 0; i < 4; i++)
#pragma unroll
            for (int j = 0; j < 4; j++)
                acc[i][j] = __builtin_amdgcn_mfma_f32_16x16x32_bf16(af[i], bfr[j], acc[i][j], 0, 0, 0);
        __syncthreads();      // drains prefetch (post-MFMA) + guards buffer reuse
        cur ^= 1;
    }
#undef GST

#pragma unroll
    for (int j = 0; j < 4; j++) {
        int col = n0 + wc * 64 + j * 16 + rsel;
        float bv;
        if (MODE == 4) bv = (n0 < 256) ? bias[col] : (n0 == 256) ? bias2[col - 256] : bias3[col - 384];
        else bv = bias[col];
#pragma unroll
        for (int i = 0; i < 4; i++) {
            int rbase = m0 + wr * 64 + i * 16 + (lane >> 4) * 4;
#pragma unroll
            for (int r2 = 0; r2 < 4; r2++) {
                int gm = rbase + r2;
                float v = acc[i][j][r2] + bv;
                if (MODE == 2) {
                    v = fmaxf(v, 0.f);
                    ((u16*)C0)[(size_t)gm * N + col] = bf16_rne(v);
                } else {
                    if (n0 < 256)       ((float*)C0)[(size_t)gm * 256 + col] = v;
                    else if (n0 == 256) ((float*)C1)[(size_t)gm * 128 + col - 256] = v;
                    else                ((u16*)C2)[(size_t)gm * 256 + col - 384] = bf16_rne(v);
                }
            }
        }
    }
}

// ---------------------------------------------------------------------------
// BM=32 x BN=256 GEMM + fused residual-add + LayerNorm. BK=64, chunk-XOR
// swizzle (r8-proven, unchanged). Grid = MPAD/32 = 832 blocks.
// LNMODE 1 (W_out+LN1): y = LN(Xres + A@Bt^T + bias); writes dstf f32 + dstb bf16.
// LNMODE 2 (ff2+LN2):   additionally writes dstq = bf16(y + posb16).
// ---------------------------------------------------------------------------
template<int LNMODE>
__global__ __launch_bounds__(256) void gemm_ln(
    const u16* __restrict__ A, const u16* __restrict__ Bt,
    const float* __restrict__ bias,
    const float* __restrict__ Xres, const float* __restrict__ g,
    const float* __restrict__ be, const u16* __restrict__ posb,
    float* __restrict__ dstf, u16* __restrict__ dstb, u16* __restrict__ dstq,
    int K, int Mguard)
{
    __shared__ __align__(16) u16 As[32 * 64];    // 4 KB
    __shared__ __align__(16) u16 Bs[256 * 64];   // 32 KB
    __shared__ float redS[32][4], redQ[32][4], mrow[32], irow[32];

    const int tid = threadIdx.x;
    const int wid = tid >> 6;
    const int wc = wid;
    const int lane = tid & 63;

    const int nwg = gridDim.x;          // 832, % 8 == 0
    const int q = nwg >> 3;
    const int wg = (blockIdx.x & 7) * q + (blockIdx.x >> 3);
    const int m0 = wg * 32;

    f32x4 acc[2][4] = {};

    // staging: slot(row=tid>>3, chunk=tid&7) sources global chunk (tid&7)^((tid>>3)&7)
    const int csw = ((tid & 7) ^ ((tid >> 3) & 7)) * 8;
    const u16* a0 = A + (size_t)(m0 + (tid >> 3)) * K + csw;
    const u16* b0 = Bt + (size_t)(tid >> 3) * K + csw;

    const int gsel = lane >> 4;         // 0..3
    const int rsel = lane & 15;
    const int swz = rsel & 7;

    for (int k0 = 0; k0 < K; k0 += 64) {
        // A: 256 chunks = 1 gload/thread; wave w covers slots w*64..w*64+63
        __builtin_amdgcn_global_load_lds((AS1 void*)(a0 + k0),
                                         (AS3 void*)(As + wid * 512), 16, 0, 0);
        // B: 2048 chunks = 8 passes
#pragma unroll
        for (int ii = 0; ii < 8; ii++)
            __builtin_amdgcn_global_load_lds((AS1 void*)(b0 + (size_t)ii * 32 * K + k0),
                                             (AS3 void*)(Bs + ii * 2048 + wid * 512), 16, 0, 0);
        __syncthreads();

#pragma unroll
        for (int s = 0; s < 2; s++) {            // kk = s*32, chunk base cb = s*4
            const int cb = s * 4;
            bf16x8 af[2], bfr[4];
#pragma unroll
            for (int i = 0; i < 2; i++)
                af[i] = *reinterpret_cast<const bf16x8*>(
                    &As[(i * 16 + rsel) * 64 + (((cb + gsel) ^ swz) * 8)]);
#pragma unroll
            for (int j = 0; j < 4; j++)
                bfr[j] = *reinterpret_cast<const bf16x8*>(
                    &Bs[(wc * 64 + j * 16 + rsel) * 64 + (((cb + gsel) ^ swz) * 8)]);
#pragma unroll
            for (int i = 0; i < 2; i++)
#pragma unroll
                for (int j = 0; j < 4; j++)
                    acc[i][j] = __builtin_amdgcn_mfma_f32_16x16x32_bf16(af[i], bfr[j], acc[i][j], 0, 0, 0);
        }
        __syncthreads();
    }

    float bias_j[4], g_j[4], be_j[4];
#pragma unroll
    for (int j = 0; j < 4; j++) {
        int col = wc * 64 + j * 16 + rsel;
        bias_j[j] = bias[col]; g_j[j] = g[col]; be_j[j] = be[col];
    }

    // fold bias + residual into acc; butterfly row-sums over the 16 rsel lanes
#pragma unroll
    for (int i = 0; i < 2; i++)
#pragma unroll
    for (int r = 0; r < 4; r++) {
        int row = i * 16 + gsel * 4 + r;
        int grow = m0 + row;
        float s = 0.f, qq = 0.f;
#pragma unroll
        for (int j = 0; j < 4; j++) {
            int col = wc * 64 + j * 16 + rsel;
            float xr = (grow < MTOT) ? Xres[(size_t)grow * 256 + col] : 0.f;
            float v = acc[i][j][r] + bias_j[j] + xr;
            acc[i][j][r] = v;
            s += v; qq += v * v;
        }
#pragma unroll
        for (int m = 1; m <= 8; m <<= 1) {
            s += __shfl_xor(s, m, 64);
            qq += __shfl_xor(qq, m, 64);
        }
        if (rsel == 0) { redS[row][wc] = s; redQ[row][wc] = qq; }
    }
    __syncthreads();
    if (tid < 32) {
        float s  = redS[tid][0] + redS[tid][1] + redS[tid][2] + redS[tid][3];
        float qq = redQ[tid][0] + redQ[tid][1] + redQ[tid][2] + redQ[tid][3];
        float mean = s * (1.f / 256.f);
        float var  = qq * (1.f / 256.f) - mean * mean;
        mrow[tid] = mean;
        irow[tid] = rsqrtf(var + 1e-5f);
    }
    __syncthreads();

#pragma unroll
    for (int i = 0; i < 2; i++)
#pragma unroll
    for (int r = 0; r < 4; r++) {
        int row = i * 16 + gsel * 4 + r;
        int grow = m0 + row;
        if (grow >= Mguard) continue;
        float mean = mrow[row], inv = irow[row];
#pragma unroll
        for (int j = 0; j < 4; j++) {
            int col = wc * 64 + j * 16 + rsel;
            float y = (acc[i][j][r] - mean) * inv * g_j[j] + be_j[j];
            dstf[(size_t)grow * 256 + col] = y;
            dstb[(size_t)grow * 256 + col] = bf16_rne(y);
            if (LNMODE == 2) {
                float pv = (grow < MTOT) ? bf16_to_f(posb[(size_t)grow * 256 + col]) : 0.f;
                dstq[(size_t)grow * 256 + col] = bf16_rne(y + pv);
            }
        }
    }
}

// ---------------------------------------------------------------------------
// Multi-scale deformable sampling with inline softmax (r5/r7/r8-proven);
// value bf16, 4 threads per (b,s,h), 8 channels each; XCD-chunk swizzle.
// ---------------------------------------------------------------------------
__global__ __launch_bounds__(256) void msdeform_kernel(
    const u16* __restrict__ value, const float* __restrict__ off,
    const float* __restrict__ logits, const float* __restrict__ ref,
    u16* __restrict__ out)
{
    const int total = MTOT * NH * 4;
    const int Q = 415, R = 4;
    int bid = blockIdx.x;
    int xcd = bid & 7, cidx = bid >> 3;
    int wg = (xcd < R ? xcd * (Q + 1) : R * (Q + 1) + (xcd - R) * Q) + cidx;
    int t = wg * 256 + (int)threadIdx.x;
    if (t >= total) return;
    int c8 = t & 3;
    int h  = (t >> 2) & 7;
    int bs = t >> 5;
    int b  = (bs >= S_TOK) ? 1 : 0;

    const int Ws[4] = {100, 50, 25, 13};
    const int Hs[4] = {100, 50, 25, 13};
    const int st[4] = {0, 10000, 12500, 13125};

    const float* offp = off    + ((size_t)bs * NH + h) * 32;
    const float* lgp  = logits + ((size_t)bs * NH + h) * 16;
    const float* refp = ref    + (size_t)bs * NL * 2;

    float lw[16];
    {
        float4 a0 = ((const float4*)lgp)[0];
        float4 a1 = ((const float4*)lgp)[1];
        float4 a2 = ((const float4*)lgp)[2];
        float4 a3 = ((const float4*)lgp)[3];
        lw[0]=a0.x; lw[1]=a0.y; lw[2]=a0.z; lw[3]=a0.w;
        lw[4]=a1.x; lw[5]=a1.y; lw[6]=a1.z; lw[7]=a1.w;
        lw[8]=a2.x; lw[9]=a2.y; lw[10]=a2.z; lw[11]=a2.w;
        lw[12]=a3.x; lw[13]=a3.y; lw[14]=a3.z; lw[15]=a3.w;
        float mx = lw[0];
#pragma unroll
        for (int i = 1; i < 16; i++) mx = fmaxf(mx, lw[i]);
        float s = 0.f;
#pragma unroll
        for (int i = 0; i < 16; i++) { lw[i] = __expf(lw[i] - mx); s += lw[i]; }
        float inv = 1.f / s;
#pragma unroll
        for (int i = 0; i < 16; i++) lw[i] *= inv;
    }

    float acc[8] = {};

#pragma unroll
    for (int l = 0; l < NL; l++) {
        const int W = Ws[l], H = Hs[l];
        const u16* vbase = value + ((size_t)b * S_TOK + st[l]) * D_MODEL + h * HD + c8 * 8;
        const float fW = (float)W, fH = (float)H;
        const float rxw = fmaf(refp[l * 2 + 0], fW, -0.5f);
        const float ryh = fmaf(refp[l * 2 + 1], fH, -0.5f);
#pragma unroll
        for (int p = 0; p < NP; p++) {
            float x = rxw + offp[l * 8 + p * 2 + 0];
            float y = ryh + offp[l * 8 + p * 2 + 1];
            float a = lw[l * 4 + p];
            float x0f = floorf(x), y0f = floorf(y);
            float wx1 = x - x0f, wy1 = y - y0f;
            float wx0 = 1.f - wx1, wy0 = 1.f - wy1;
            int ix0 = (int)x0f, iy0 = (int)y0f;
#pragma unroll
            for (int dy = 0; dy < 2; dy++) {
                int yi = iy0 + dy;
                if (yi < 0 || yi >= H) continue;
                float wy = dy ? wy1 : wy0;
#pragma unroll
                for (int dx = 0; dx < 2; dx++) {
                    int xi = ix0 + dx;
                    if (xi < 0 || xi >= W) continue;
                    float wgt = (dx ? wx1 : wx0) * wy * a;
                    uint4 gv = *(const uint4*)(vbase + (size_t)(yi * W + xi) * D_MODEL);
                    union { uint32_t q; float f; } lo, hi;
                    lo.q = gv.x << 16; hi.q = gv.x & 0xffff0000u;
                    acc[0] = fmaf(lo.f, wgt, acc[0]); acc[1] = fmaf(hi.f, wgt, acc[1]);
                    lo.q = gv.y << 16; hi.q = gv.y & 0xffff0000u;
                    acc[2] = fmaf(lo.f, wgt, acc[2]); acc[3] = fmaf(hi.f, wgt, acc[3]);
                    lo.q = gv.z << 16; hi.q = gv.z & 0xffff0000u;
                    acc[4] = fmaf(lo.f, wgt, acc[4]); acc[5] = fmaf(hi.f, wgt, acc[5]);
                    lo.q = gv.w << 16; hi.q = gv.w & 0xffff0000u;
                    acc[6] = fmaf(lo.f, wgt, acc[6]); acc[7] = fmaf(hi.f, wgt, acc[7]);
                }
            }
        }
    }
    uint4 o;
    o.x = ((uint32_t)bf16_rne(acc[1]) << 16) | bf16_rne(acc[0]);
    o.y = ((uint32_t)bf16_rne(acc[3]) << 16) | bf16_rne(acc[2]);
    o.z = ((uint32_t)bf16_rne(acc[5]) << 16) | bf16_rne(acc[4]);
    o.w = ((uint32_t)bf16_rne(acc[7]) << 16) | bf16_rne(acc[6]);
    ((uint4*)out)[((size_t)bs * NH + h) * 4 + c8] = o;
}

// ---------------------------------------------------------------------------
extern "C" void kernel_launch(void* const* d_in, const int* in_sizes, int n_in,
                              void* d_out, int out_size, void* d_ws, size_t ws_size,
                              hipStream_t stream)
{
    const float* src    = (const float*)d_in[0];
    const float* pos    = (const float*)d_in[1];
    const float* vr     = (const float*)d_in[2];
    const float* W_off  = (const float*)d_in[3];
    const float* b_off  = (const float*)d_in[4];
    const float* W_attn = (const float*)d_in[5];
    const float* b_attn = (const float*)d_in[6];
    const float* W_val  = (const float*)d_in[7];
    const float* b_val  = (const float*)d_in[8];
    const float* W_out  = (const float*)d_in[9];
    const float* b_out  = (const float*)d_in[10];
    const float* g1     = (const float*)d_in[11];
    const float* be1    = (const float*)d_in[12];
    const float* W_ff1  = (const float*)d_in[13];
    const float* b_ff1  = (const float*)d_in[14];
    const float* W_ff2  = (const float*)d_in[15];
    const float* b_ff2  = (const float*)d_in[16];
    const float* g2     = (const float*)d_in[17];
    const float* be2    = (const float*)d_in[18];
    float* out = (float*)d_out;

    uint8_t* wp = (uint8_t*)d_ws;
    auto alloc = [&](size_t bytes) { uint8_t* p = wp; wp += (bytes + 255) & ~(size_t)255; return p; };
    float* refb   = (float*)alloc((size_t)MTOT * 8 * 4);
    float* Ybuf   = (float*)alloc((size_t)MPAD * 256 * 4);
    float* Xf     = (float*)alloc((size_t)MPAD * 256 * 4);
    // [offb | attb | valb16] contiguous: all dead during FFN -> aliased by ffb16
    float* offb   = (float*)alloc((size_t)MPAD * 256 * 4);
    float* attb   = (float*)alloc((size_t)MPAD * 128 * 4);
    u16*   valb16 = (u16*)alloc((size_t)MPAD * 256 * 2);
    uint8_t* slabB = alloc((size_t)MPAD * 256 * 2);         // Xb16 / samb16
    uint8_t* slabC = alloc((size_t)MPAD * 256 * 2);         // Qb16 / Yb16
    u16*   posb16 = (u16*)alloc((size_t)MPAD * 256 * 2);
    u16* Wt = (u16*)alloc((size_t)NLAYERS * WT_L * 2);

    u16* Xb16   = (u16*)slabB;
    u16* samb16 = (u16*)slabB;
    u16* Qb16   = (u16*)slabC;
    u16* Yb16   = (u16*)slabC;
    u16* ffb16  = (u16*)offb;   // 27.25 + 13.63 + 13.63 MB == MPAD*1024*2 B exactly

    const int GY = MPAD / 128;            // 208
    const int GLN = MPAD / 32;            // 832
    const int MSD_BLOCKS = (MTOT * NH * 4 + 255) / 256;  // 3324

    wprep_kernel<<<(NLAYERS * WT_L + 255) / 256, 256, 0, stream>>>(
        W_val, W_off, W_attn, W_out, W_ff1, W_ff2, Wt);
    refpoints_kernel<<<(MTOT + 255) / 256, 256, 0, stream>>>(vr, refb);
    conv0_kernel<<<(MTOT * 64 + 255) / 256, 256, 0, stream>>>(src, pos, Xb16, Qb16, posb16);

    for (int l = 0; l < NLAYERS; l++) {
        const float* Xres = (l == 0) ? src : Xf;
        const u16* Wl = Wt + (size_t)l * WT_L;

        // off|attn|value fused: Q @ [Wo|Wa] and X @ Wv, one dispatch (N=640)
        gemm_bf16<4><<<dim3(5, GY), 256, 0, stream>>>(
            Qb16, Xb16, Wl + WT_OA2,
            b_off + l * 256, b_attn + l * 128, b_val + l * 256,
            offb, attb, valb16, 640, 256);
        // sampled -> samb16 (overwrites dead Xb16); softmax fused inside
        msdeform_kernel<<<MSD_BLOCKS, 256, 0, stream>>>(
            valb16, offb, attb, refb, samb16);
        // Y = LN(Xres + sampled @ W_out + b_out): fused epilogue, BM=32/BK=64
        gemm_ln<1><<<GLN, 256, 0, stream>>>(
            samb16, Wl + WT_OOUT, b_out + l * 256,
            Xres, g1 + l * 256, be1 + l * 256, nullptr,
            Ybuf, Yb16, nullptr, 256, MPAD);
        // ff1: bf16 relu(Y @ Wf1 + b), one dispatch into ffb16 (aliases offb..valb16)
        gemm_bf16<2><<<dim3(8, GY), 256, 0, stream>>>(
            Yb16, nullptr, Wl + WT_OF1, b_ff1 + l * DFF, nullptr, nullptr,
            ffb16, nullptr, nullptr, 1024, 256);
        // X' = LN(Y + ff @ Wf2 + b): fused epilogue, BM=32/BK=64
        float* dst = (l == NLAYERS - 1) ? out : Xf;
        int mg = (l == NLAYERS - 1) ? MTOT : MPAD;
        gemm_ln<2><<<GLN, 256, 0, stream>>>(
            ffb16, Wl + WT_OF2, b_ff2 + l * 256,
            Ybuf, g2 + l * 256, be2 + l * 256, posb16,
            dst, Xb16, Qb16, 1024, mg);
    }
}